// Round 10
// baseline (493.068 us; speedup 1.0000x reference)
//
#include <hip/hip_runtime.h>
#include <math.h>

#define NATOMS 10000
#define NEDGES 320000
#define RC_F 5.0f
#define PI_F 3.14159265358979323846f

// ---- workspace layout (in floats) ----
#define WS_SEMB   0         // 12 floats
#define WS_CNT    16        // NATOMS ints
#define WS_OFFS   10016     // NATOMS ints (run start per atom)
#define WS_CURSOR 20016     // NATOMS ints
#define WS_EIDX   30016     // NEDGES ints: packed (t<<20)|e per atom-run
#define WS_SA     350080    // NEDGES*32 floats: R[0..23] (+pad), 128B records, slot = edge id
#define WS_SB     10590080  // NEDGES*32 floats: R[24..47], rhat, t (+pad), 128B records

// multinomial term tables (global component index 0..34)
__device__ __constant__ int   d_PWA[35] = {0, 0,0,1, 0,0,0,1,1,2, 0,0,0,0,1,1,1,2,2,3, 0,0,0,0,0,1,1,1,1,2,2,2,3,3,4};
__device__ __constant__ int   d_PWB[35] = {0, 0,1,0, 0,1,2,0,1,0, 0,1,2,3,0,1,2,0,1,0, 0,1,2,3,4,0,1,2,3,0,1,2,0,1,0};
__device__ __constant__ int   d_PWC[35] = {0, 1,0,0, 2,1,0,1,0,0, 3,2,1,0,2,1,0,1,0,0, 4,3,2,1,0,3,2,1,0,2,1,0,1,0,0};
__device__ __constant__ float d_NM[35]  = {1.f, 1.f,1.f,1.f, 1.f,2.f,1.f,2.f,2.f,1.f,
                                           1.f,3.f,3.f,1.f,3.f,6.f,3.f,3.f,3.f,1.f,
                                           1.f,4.f,6.f,4.f,1.f,4.f,12.f,12.f,4.f,6.f,12.f,6.f,4.f,4.f,1.f};
__device__ __constant__ int   d_LBLK[35]= {0, 1,1,1, 2,2,2,2,2,2, 3,3,3,3,3,3,3,3,3,3, 4,4,4,4,4,4,4,4,4,4,4,4,4,4,4};
__device__ __constant__ int   d_L6[6]   = {0,1,4,10,20,35};

__device__ __forceinline__ float siluf(float x) { return x / (1.0f + __expf(-x)); }

__device__ __forceinline__ float psel(float x, int p) {
  float x2 = x * x;
  float r = 1.0f;
  r = (p == 1) ? x : r;
  r = (p == 2) ? x2 : r;
  r = (p == 3) ? x2 * x : r;
  r = (p == 4) ? x2 * x2 : r;
  return r;
}

// ---------------- k_prep: fused hist + alloc + semb (deterministic, no global atomics) ----------------
// Every block builds the FULL per-atom histogram in LDS from the shared (L2/L3-resident)
// first_atom stream, then computes its own 256-atom range's base offset and scan.
__global__ __launch_bounds__(256) void k_prep(
    const int* __restrict__ first_atom,
    const float* __restrict__ Ws1, const float* __restrict__ bs1,
    const float* __restrict__ Ws2, const float* __restrict__ bs2,
    float* __restrict__ ws)
{
  __shared__ int hist[NATOMS];          // 40 KB
  __shared__ int red[4];
  __shared__ int wsum[4];
  int tid = threadIdx.x, lane = tid & 63, wv = tid >> 6;

  for (int i = tid; i < NATOMS; i += 256) hist[i] = 0;
  __syncthreads();
  for (int i = tid; i < NEDGES; i += 256) atomicAdd(&hist[first_atom[i]], 1);
  __syncthreads();

  int abase = blockIdx.x * 256;
  // base = sum of hist[0 .. abase)
  int p = 0;
  for (int i = tid; i < abase; i += 256) p += hist[i];
  #pragma unroll
  for (int d = 32; d > 0; d >>= 1) p += __shfl_down(p, d, 64);
  if (lane == 0) red[wv] = p;
  __syncthreads();
  int base = red[0] + red[1] + red[2] + red[3];

  int a = abase + tid;
  int c = (a < NATOMS) ? hist[a] : 0;
  int inc = c;
  #pragma unroll
  for (int d = 1; d < 64; d <<= 1) {
    int v = __shfl_up(inc, d, 64);
    if (lane >= d) inc += v;
  }
  if (lane == 63) wsum[wv] = inc;
  __syncthreads();
  int woff = base;
  for (int w = 0; w < wv; w++) woff += wsum[w];
  int o0 = woff + inc - c;
  if (a < NATOMS) {
    ((int*)(ws + WS_OFFS))[a]   = o0;
    ((int*)(ws + WS_CURSOR))[a] = o0;
    ((int*)(ws + WS_CNT))[a]    = c;
  }
  if (blockIdx.x == 0 && tid < 12) {
    int t = tid >> 2, s = tid & 3;
    float acc = bs2[s];
    for (int j = 0; j < 16; j++) acc += tanhf(Ws1[t * 16 + j] + bs1[j]) * Ws2[j * 4 + s];
    ws[WS_SEMB + tid] = acc;
  }
}

// ---------------- k_edge: dense MLP -> half-record LDS rows -> 2 coalesced bursts ----------------
// Record split into SA (R[0..23]) and SB (R[24..47], rhat, t) so the LDS staging
// buffer is 28 floats/record (reused across the two phases) -> 7KB/wave -> ~20
// waves/CU (was 12) to hide s_load/store latency.
__global__ __launch_bounds__(256) void k_edge(
    const float* __restrict__ rij, const int* __restrict__ species,
    const int* __restrict__ first_atom, const int* __restrict__ second_atom,
    const float* __restrict__ Wr1, const float* __restrict__ br1,
    const float* __restrict__ Wr2, const float* __restrict__ br2,
    float* __restrict__ ws)
{
  __shared__ __align__(16) float sRec[4][64 * 28];   // 28 KB/block
  int tid = threadIdx.x, lane = tid & 63, wv = tid >> 6;
  int e = blockIdx.x * 256 + tid;                    // NEDGES = 1250*256 exact
  int* cursor = (int*)(ws + WS_CURSOR);
  int* eidx   = (int*)(ws + WS_EIDX);
  float* myrow = &sRec[wv][lane * 28];

  // issue gather chain + atomic + eidx store early; latency overlaps the MLP
  int a = first_atom[e];
  int t = species[second_atom[e]];
  int pos = atomicAdd(&cursor[a], 1);
  eidx[pos] = e | (t << 20);

  float x = rij[e * 3 + 0], y = rij[e * 3 + 1], z = rij[e * 3 + 2];
  float d = sqrtf(x * x + y * y + z * z + 1e-12f);
  float invd = 1.0f / d;
  float fc = (d < RC_F) ? 0.5f * (__cosf(PI_F * d / RC_F) + 1.0f) : 0.0f;

  float bes[8];
  float sq = sqrtf(2.0f / RC_F);
  #pragma unroll
  for (int k = 0; k < 8; k++) bes[k] = sq * __sinf((float)(k + 1) * (PI_F / RC_F) * d) * invd;

  // layer 1: 8 -> 64 (Wr1 wave-uniform -> scalar loads)
  float h1[64];
  #pragma unroll
  for (int j4 = 0; j4 < 16; j4++) {
    float acc[4];
    #pragma unroll
    for (int u = 0; u < 4; u++) acc[u] = br1[j4 * 4 + u];
    #pragma unroll
    for (int k = 0; k < 8; k++) {
      #pragma unroll
      for (int u = 0; u < 4; u++) acc[u] += bes[k] * Wr1[k * 64 + j4 * 4 + u];
    }
    #pragma unroll
    for (int u = 0; u < 4; u++) h1[j4 * 4 + u] = siluf(acc[u]);
  }

  int ebase = blockIdx.x * 256 + wv * 64;            // first edge of this wave
  const float* buf = &sRec[wv][0];
  int f4 = lane & 7, rloc = lane >> 3;

  // ---- phase A: outputs 0..23 ----
  for (int j4 = 0; j4 < 6; j4++) {
    float acc[4];
    #pragma unroll
    for (int u = 0; u < 4; u++) acc[u] = br2[j4 * 4 + u];
    #pragma unroll
    for (int k = 0; k < 64; k++) {
      #pragma unroll
      for (int u = 0; u < 4; u++) acc[u] += h1[k] * Wr2[k * 48 + j4 * 4 + u];
    }
    *(float4*)(myrow + j4 * 4) = make_float4(siluf(acc[0]) * fc, siluf(acc[1]) * fc,
                                             siluf(acc[2]) * fc, siluf(acc[3]) * fc);
  }
  {
    float* gbase = ws + WS_SA + (size_t)ebase * 32;
    if (f4 < 6) {
      #pragma unroll
      for (int q = 0; q < 8; q++) {
        int g4 = q * 64 + lane;                      // r = g4>>3, f4 = g4&7
        float4 v = *(const float4*)(buf + (g4 >> 3) * 28 + f4 * 4);
        *(float4*)(gbase + (size_t)g4 * 4) = v;      // contiguous 1KB span per q
      }
    }
  }

  // ---- phase B: outputs 24..47 + rhat/t (LDS rows reused; same-wave DS order is safe) ----
  for (int j4 = 6; j4 < 12; j4++) {
    float acc[4];
    #pragma unroll
    for (int u = 0; u < 4; u++) acc[u] = br2[j4 * 4 + u];
    #pragma unroll
    for (int k = 0; k < 64; k++) {
      #pragma unroll
      for (int u = 0; u < 4; u++) acc[u] += h1[k] * Wr2[k * 48 + j4 * 4 + u];
    }
    *(float4*)(myrow + (j4 - 6) * 4) = make_float4(siluf(acc[0]) * fc, siluf(acc[1]) * fc,
                                                   siluf(acc[2]) * fc, siluf(acc[3]) * fc);
  }
  *(float4*)(myrow + 24) = make_float4(x * invd, y * invd, z * invd, 0.0f);
  {
    float* gbase = ws + WS_SB + (size_t)ebase * 32;
    if (f4 < 7) {
      #pragma unroll
      for (int q = 0; q < 8; q++) {
        int g4 = q * 64 + lane;
        float4 v = *(const float4*)(buf + (g4 >> 3) * 28 + f4 * 4);
        *(float4*)(gbase + (size_t)g4 * 4) = v;
      }
    }
  }
}

// ---------------- k_atom: one wave per atom, 16-lane/record gather from SA/SB, no barriers ----------------
__global__ __launch_bounds__(128) void k_atom(
    const float* __restrict__ ws,
    const float* __restrict__ Wa1, const float* __restrict__ ba1,
    const float* __restrict__ Wa2, const float* __restrict__ ba2,
    const float* __restrict__ Wa3, const float* __restrict__ ba3,
    float* __restrict__ out)
{
  // per-wave: [0..511] double-buffered 4-record stage, [512..1375] G (col 35 = G0),
  //           [1376..1567] feat, [1568..1631] h
  __shared__ __align__(16) float sScr[2][1696];
  int tid = threadIdx.x;
  int lane = tid & 63, wv = tid >> 6;
  int a = blockIdx.x * 2 + wv;          // NATOMS = 5000*2 exact
  float* sStage = &sScr[wv][0];
  float* sG     = &sScr[wv][512];
  float* sFeat  = &sScr[wv][1376];
  float* sH     = &sScr[wv][1568];

  const int* offs = (const int*)(ws + WS_OFFS);
  const int* cnt  = (const int*)(ws + WS_CNT);
  const int* eidx = (const int*)(ws + WS_EIDX);
  int start = offs[a], len = cnt[a], end = start + len;

  const int c = lane;
  bool isc = (c < 35);
  int pa = 0, pb = 0, pcw = 0, lb = 0;
  if (isc) { pa = d_PWA[c]; pb = d_PWB[c]; pcw = d_PWC[c]; lb = d_LBLK[c]; }
  int rdir = lane - 35;
  bool isd = (rdir >= 0) && (rdir < 8);
  int rl = lane >> 4, fl = lane & 15;   // gather role: record rl, float4 fl
  // source array + offset: fl<6 -> SA[fl]; fl 6..12 -> SB[fl-6]; fl 13..15 -> dup SB[6]
  const float* gsrc = ws + (fl < 6 ? WS_SA : WS_SB);
  int foff = (fl < 6) ? fl : ((fl < 13) ? fl - 6 : 6);
  // LDS landing slot fl*4 reproduces the 52-float record layout (B maps to 24+(fl-6)*4 = fl*4)

  float gc[3][8];
  #pragma unroll
  for (int t2 = 0; t2 < 3; t2++)
    #pragma unroll
    for (int r = 0; r < 8; r++) gc[t2][r] = 0.0f;
  float g0[3] = {0.0f, 0.0f, 0.0f};

#define CORE(T)                                                               \
  if (isc) {                                                                  \
    float4 rt = *(const float4*)(rb + 48);                                    \
    float comp = psel(rt.x, pa) * psel(rt.y, pb) * psel(rt.z, pcw);           \
    float4 Ra = *(const float4*)(rb + 8 + 8 * lb);                            \
    float4 Rb = *(const float4*)(rb + 12 + 8 * lb);                           \
    gc[T][0] += comp * Ra.x; gc[T][1] += comp * Ra.y;                         \
    gc[T][2] += comp * Ra.z; gc[T][3] += comp * Ra.w;                         \
    gc[T][4] += comp * Rb.x; gc[T][5] += comp * Rb.y;                         \
    gc[T][6] += comp * Rb.z; gc[T][7] += comp * Rb.w;                         \
  } else if (isd) {                                                           \
    g0[T] += rb[rdir];                                                        \
  }

  for (int cb = start; cb < end; cb += 64) {
    int m = end - cb; if (m > 64) m = 64;
    int pp = cb + lane;
    int packed = eidx[pp < end ? pp : start];     // coalesced chunk of indices
    // prefetch round 0 (4 records, 16 lanes each)
    int sl = rl; if (sl >= m) sl = m - 1;
    int pk = __shfl(packed, sl, 64);
    float4 v = *(const float4*)(gsrc + (size_t)(pk & 0xFFFFF) * 32 + foff * 4);
    for (int g = 0; g < m; g += 4) {
      float* buf = sStage + (((g >> 2) & 1) << 8);
      *(float4*)(buf + rl * 64 + fl * 4) = v;     // ds_write staged round
      if (g + 4 < m) {                            // prefetch next round into regs
        int sl2 = g + 4 + rl; if (sl2 >= m) sl2 = m - 1;
        int pk2 = __shfl(packed, sl2, 64);
        v = *(const float4*)(gsrc + (size_t)(pk2 & 0xFFFFF) * 32 + foff * 4);
      }
      int gm = m - g; if (gm > 4) gm = 4;
      for (int j = 0; j < gm; j++) {
        int t = __shfl(packed, g + j, 64) >> 20;  // wave-uniform species
        const float* rb = buf + j * 64;
        if (t == 0)      { CORE(0) }
        else if (t == 1) { CORE(1) }
        else             { CORE(2) }
      }
    }
  }
#undef CORE

  // transpose G into LDS (same-wave, no barrier)
  if (isc) {
    #pragma unroll
    for (int t2 = 0; t2 < 3; t2++)
      #pragma unroll
      for (int r = 0; r < 8; r++) sG[(t2 * 8 + r) * 36 + c] = gc[t2][r];
  } else if (isd) {
    #pragma unroll
    for (int t2 = 0; t2 < 3; t2++) sG[(t2 * 8 + rdir) * 36 + 35] = g0[t2];
  }

  // contraction: lane owns feats {lane, lane+64, lane+128}; f=(blk*8+rr)*4+s
  int s = lane & 3;
  float se0 = ws[WS_SEMB + s], se1 = ws[WS_SEMB + 4 + s], se2 = ws[WS_SEMB + 8 + s];
  float fout[3];
  #pragma unroll
  for (int u = 0; u < 3; u++) {
    int f = lane + 64 * u;
    int blk = f >> 5, rr = (f >> 2) & 7;
    float acc;
    if (blk == 0) {
      acc = se0 * sG[(0 + rr) * 36 + 35] + se1 * sG[(8 + rr) * 36 + 35] + se2 * sG[(16 + rr) * 36 + 35];
    } else {
      int c0 = d_L6[blk - 1], c1 = d_L6[blk];
      acc = 0.0f;
      for (int cc = c0; cc < c1; cc++) {
        float A = se0 * sG[(0 + rr) * 36 + cc] + se1 * sG[(8 + rr) * 36 + cc] + se2 * sG[(16 + rr) * 36 + cc];
        acc += d_NM[cc] * A * A;
      }
    }
    fout[u] = acc;
  }
  #pragma unroll
  for (int u = 0; u < 3; u++) sFeat[lane + 64 * u] = fout[u];

  // MLP layer 1: 192 -> 64
  {
    float a0 = 0.f, a1 = 0.f, a2 = 0.f, a3 = 0.f;
    for (int k4 = 0; k4 < 48; k4++) {
      float4 f4 = *(const float4*)(sFeat + k4 * 4);
      const float* w = Wa1 + (k4 * 4) * 64 + lane;
      a0 += f4.x * w[0];
      a1 += f4.y * w[64];
      a2 += f4.z * w[128];
      a3 += f4.w * w[192];
    }
    sH[lane] = siluf(a0 + a1 + a2 + a3 + ba1[lane]);
  }

  // MLP layer 2: 64 -> 64, layer 3 + wave reduction
  {
    float a0 = 0.f, a1 = 0.f, a2 = 0.f, a3 = 0.f;
    for (int k4 = 0; k4 < 16; k4++) {
      float4 h4 = *(const float4*)(sH + k4 * 4);
      const float* w = Wa2 + (k4 * 4) * 64 + lane;
      a0 += h4.x * w[0];
      a1 += h4.y * w[64];
      a2 += h4.z * w[128];
      a3 += h4.w * w[192];
    }
    float h2 = siluf(a0 + a1 + a2 + a3 + ba2[lane]);
    float pr = h2 * Wa3[lane];
    #pragma unroll
    for (int off = 32; off > 0; off >>= 1) pr += __shfl_down(pr, off, 64);
    if (lane == 0) out[a] = pr + ba3[0];
  }
}

extern "C" void kernel_launch(void* const* d_in, const int* in_sizes, int n_in,
                              void* d_out, int out_size, void* d_ws, size_t ws_size,
                              hipStream_t stream)
{
  const float* rij         = (const float*)d_in[0];
  const int*   species     = (const int*)  d_in[1];
  const int*   first_atom  = (const int*)  d_in[2];
  const int*   second_atom = (const int*)  d_in[3];
  const float* Wr1 = (const float*)d_in[4];
  const float* br1 = (const float*)d_in[5];
  const float* Wr2 = (const float*)d_in[6];
  const float* br2 = (const float*)d_in[7];
  const float* Ws1 = (const float*)d_in[8];
  const float* bs1 = (const float*)d_in[9];
  const float* Ws2 = (const float*)d_in[10];
  const float* bs2 = (const float*)d_in[11];
  const float* Wa1 = (const float*)d_in[12];
  const float* ba1 = (const float*)d_in[13];
  const float* Wa2 = (const float*)d_in[14];
  const float* ba2 = (const float*)d_in[15];
  const float* Wa3 = (const float*)d_in[16];
  const float* ba3 = (const float*)d_in[17];
  float* ws  = (float*)d_ws;
  float* out = (float*)d_out;

  k_prep<<<40, 256, 0, stream>>>(first_atom, Ws1, bs1, Ws2, bs2, ws);
  k_edge<<<NEDGES / 256, 256, 0, stream>>>(rij, species, first_atom, second_atom,
                                           Wr1, br1, Wr2, br2, ws);
  k_atom<<<NATOMS / 2, 128, 0, stream>>>(ws, Wa1, ba1, Wa2, ba2, Wa3, ba3, out);
}

// Round 11
// 218.415 us; speedup vs baseline: 2.2575x; 2.2575x over previous
//
#include <hip/hip_runtime.h>
#include <math.h>

#define NATOMS 10000
#define NEDGES 320000
#define RC_F 5.0f
#define PI_F 3.14159265358979323846f

// ---- workspace layout (in floats) ----
#define WS_SEMB   0         // 12 floats
#define WS_GTOT   12        // 1 int global allocation cursor
#define WS_CNT    16        // NATOMS ints
#define WS_OFFS   10016     // NATOMS ints (run start per atom)
#define WS_CURSOR 20016     // NATOMS ints
#define WS_EIDX   30016     // NEDGES ints: packed (t<<20)|e per atom-run
#define WS_SA     350080    // NEDGES*32 floats: R[0..23] (+pad), 128B records, slot = edge id
#define WS_SB     10590080  // NEDGES*32 floats: R[24..47], rhat, t (+pad), 128B records

// multinomial term tables (global component index 0..34)
__device__ __constant__ int   d_PWA[35] = {0, 0,0,1, 0,0,0,1,1,2, 0,0,0,0,1,1,1,2,2,3, 0,0,0,0,0,1,1,1,1,2,2,2,3,3,4};
__device__ __constant__ int   d_PWB[35] = {0, 0,1,0, 0,1,2,0,1,0, 0,1,2,3,0,1,2,0,1,0, 0,1,2,3,4,0,1,2,3,0,1,2,0,1,0};
__device__ __constant__ int   d_PWC[35] = {0, 1,0,0, 2,1,0,1,0,0, 3,2,1,0,2,1,0,1,0,0, 4,3,2,1,0,3,2,1,0,2,1,0,1,0,0};
__device__ __constant__ float d_NM[35]  = {1.f, 1.f,1.f,1.f, 1.f,2.f,1.f,2.f,2.f,1.f,
                                           1.f,3.f,3.f,1.f,3.f,6.f,3.f,3.f,3.f,1.f,
                                           1.f,4.f,6.f,4.f,1.f,4.f,12.f,12.f,4.f,4.f,1.f,12.f,6.f,4.f,1.f};
__device__ __constant__ int   d_LBLK[35]= {0, 1,1,1, 2,2,2,2,2,2, 3,3,3,3,3,3,3,3,3,3, 4,4,4,4,4,4,4,4,4,4,4,4,4,4,4};
__device__ __constant__ int   d_L6[6]   = {0,1,4,10,20,35};
// NOTE: d_NM above must match reference ordering exactly; correct table restated:
__device__ __constant__ float d_NM_OK[35] = {1.f, 1.f,1.f,1.f, 1.f,2.f,1.f,2.f,2.f,1.f,
                                             1.f,3.f,3.f,1.f,3.f,6.f,3.f,3.f,3.f,1.f,
                                             1.f,4.f,6.f,4.f,1.f,4.f,12.f,12.f,4.f,6.f,12.f,6.f,4.f,4.f,1.f};

__device__ __forceinline__ float siluf(float x) { return x / (1.0f + __expf(-x)); }

__device__ __forceinline__ float psel(float x, int p) {
  float x2 = x * x;
  float r = 1.0f;
  r = (p == 1) ? x : r;
  r = (p == 2) ? x2 : r;
  r = (p == 3) ? x2 * x : r;
  r = (p == 4) ? x2 * x2 : r;
  return r;
}

// ---------------- k_init ----------------
__global__ void k_init(const float* __restrict__ Ws1, const float* __restrict__ bs1,
                       const float* __restrict__ Ws2, const float* __restrict__ bs2,
                       float* __restrict__ ws)
{
  int tid = blockIdx.x * blockDim.x + threadIdx.x;
  int* cnt = (int*)(ws + WS_CNT);
  if (tid < NATOMS) cnt[tid] = 0;
  if (tid == 0) *(int*)(ws + WS_GTOT) = 0;
  if (tid < 12) {
    int t = tid >> 2, s = tid & 3;
    float acc = bs2[s];
    for (int j = 0; j < 16; j++) acc += tanhf(Ws1[t * 16 + j] + bs1[j]) * Ws2[j * 4 + s];
    ws[WS_SEMB + tid] = acc;
  }
}

// ---------------- k_hist: per-atom edge counts (full-occupancy global atomics) ----------------
__global__ void k_hist(const int* __restrict__ first_atom, float* __restrict__ ws)
{
  int e = blockIdx.x * blockDim.x + threadIdx.x;
  if (e < NEDGES) {
    int* cnt = (int*)(ws + WS_CNT);
    atomicAdd(&cnt[first_atom[e]], 1);
  }
}

// ---------------- k_alloc: decentralized run allocation (order-free) ----------------
__global__ __launch_bounds__(256) void k_alloc(float* __restrict__ ws)
{
  const int* cnt = (const int*)(ws + WS_CNT);
  int* offs   = (int*)(ws + WS_OFFS);
  int* cursor = (int*)(ws + WS_CURSOR);
  int* gtot = (int*)(ws + WS_GTOT);
  __shared__ int wsum[4];
  __shared__ int sbase;
  int tid = threadIdx.x;
  int lane = tid & 63, wv = tid >> 6;
  int a = blockIdx.x * 256 + tid;
  bool live = (a < NATOMS);
  int c = live ? cnt[a] : 0;
  int inc = c;
  #pragma unroll
  for (int d = 1; d < 64; d <<= 1) {
    int v = __shfl_up(inc, d, 64);
    if (lane >= d) inc += v;
  }
  if (lane == 63) wsum[wv] = inc;
  __syncthreads();
  if (tid == 0) sbase = atomicAdd(gtot, wsum[0] + wsum[1] + wsum[2] + wsum[3]);
  __syncthreads();
  int woff = sbase;
  for (int w = 0; w < wv; w++) woff += wsum[w];
  int o0 = woff + inc - c;
  if (live) { offs[a] = o0; cursor[a] = o0; }
}

// ---------------- k_edge: dense MLP -> half-record LDS rows -> 2 coalesced bursts ----------------
__global__ __launch_bounds__(256) void k_edge(
    const float* __restrict__ rij, const int* __restrict__ species,
    const int* __restrict__ first_atom, const int* __restrict__ second_atom,
    const float* __restrict__ Wr1, const float* __restrict__ br1,
    const float* __restrict__ Wr2, const float* __restrict__ br2,
    float* __restrict__ ws)
{
  __shared__ __align__(16) float sRec[4][64 * 28];   // 28 KB/block
  int tid = threadIdx.x, lane = tid & 63, wv = tid >> 6;
  int e = blockIdx.x * 256 + tid;                    // NEDGES = 1250*256 exact
  int* cursor = (int*)(ws + WS_CURSOR);
  int* eidx   = (int*)(ws + WS_EIDX);
  float* myrow = &sRec[wv][lane * 28];

  // issue gather chain + atomic + eidx store early; latency overlaps the MLP
  int a = first_atom[e];
  int t = species[second_atom[e]];
  int pos = atomicAdd(&cursor[a], 1);
  eidx[pos] = e | (t << 20);

  float x = rij[e * 3 + 0], y = rij[e * 3 + 1], z = rij[e * 3 + 2];
  float d = sqrtf(x * x + y * y + z * z + 1e-12f);
  float invd = 1.0f / d;
  float fc = (d < RC_F) ? 0.5f * (__cosf(PI_F * d / RC_F) + 1.0f) : 0.0f;

  float bes[8];
  float sq = sqrtf(2.0f / RC_F);
  #pragma unroll
  for (int k = 0; k < 8; k++) bes[k] = sq * __sinf((float)(k + 1) * (PI_F / RC_F) * d) * invd;

  // layer 1: 8 -> 64 (Wr1 wave-uniform -> scalar loads)
  float h1[64];
  #pragma unroll
  for (int j4 = 0; j4 < 16; j4++) {
    float acc[4];
    #pragma unroll
    for (int u = 0; u < 4; u++) acc[u] = br1[j4 * 4 + u];
    #pragma unroll
    for (int k = 0; k < 8; k++) {
      #pragma unroll
      for (int u = 0; u < 4; u++) acc[u] += bes[k] * Wr1[k * 64 + j4 * 4 + u];
    }
    #pragma unroll
    for (int u = 0; u < 4; u++) h1[j4 * 4 + u] = siluf(acc[u]);
  }

  int ebase = blockIdx.x * 256 + wv * 64;            // first edge of this wave
  const float* buf = &sRec[wv][0];
  int f4 = lane & 7;

  // ---- phase A: outputs 0..23 ----
  for (int j4 = 0; j4 < 6; j4++) {
    float acc[4];
    #pragma unroll
    for (int u = 0; u < 4; u++) acc[u] = br2[j4 * 4 + u];
    #pragma unroll
    for (int k = 0; k < 64; k++) {
      #pragma unroll
      for (int u = 0; u < 4; u++) acc[u] += h1[k] * Wr2[k * 48 + j4 * 4 + u];
    }
    *(float4*)(myrow + j4 * 4) = make_float4(siluf(acc[0]) * fc, siluf(acc[1]) * fc,
                                             siluf(acc[2]) * fc, siluf(acc[3]) * fc);
  }
  {
    float* gbase = ws + WS_SA + (size_t)ebase * 32;
    if (f4 < 6) {
      #pragma unroll
      for (int q = 0; q < 8; q++) {
        int g4 = q * 64 + lane;                      // r = g4>>3, f4 = g4&7
        float4 v = *(const float4*)(buf + (g4 >> 3) * 28 + f4 * 4);
        *(float4*)(gbase + (size_t)g4 * 4) = v;      // contiguous span per q
      }
    }
  }

  // ---- phase B: outputs 24..47 + rhat/t (LDS rows reused; same-wave DS order is safe) ----
  for (int j4 = 6; j4 < 12; j4++) {
    float acc[4];
    #pragma unroll
    for (int u = 0; u < 4; u++) acc[u] = br2[j4 * 4 + u];
    #pragma unroll
    for (int k = 0; k < 64; k++) {
      #pragma unroll
      for (int u = 0; u < 4; u++) acc[u] += h1[k] * Wr2[k * 48 + j4 * 4 + u];
    }
    *(float4*)(myrow + (j4 - 6) * 4) = make_float4(siluf(acc[0]) * fc, siluf(acc[1]) * fc,
                                                   siluf(acc[2]) * fc, siluf(acc[3]) * fc);
  }
  *(float4*)(myrow + 24) = make_float4(x * invd, y * invd, z * invd, 0.0f);
  {
    float* gbase = ws + WS_SB + (size_t)ebase * 32;
    if (f4 < 7) {
      #pragma unroll
      for (int q = 0; q < 8; q++) {
        int g4 = q * 64 + lane;
        float4 v = *(const float4*)(buf + (g4 >> 3) * 28 + f4 * 4);
        *(float4*)(gbase + (size_t)g4 * 4) = v;
      }
    }
  }
}

// ---------------- k_atom: one wave per atom, 16-lane/record gather from SA/SB, no barriers ----------------
__global__ __launch_bounds__(128) void k_atom(
    const float* __restrict__ ws,
    const float* __restrict__ Wa1, const float* __restrict__ ba1,
    const float* __restrict__ Wa2, const float* __restrict__ ba2,
    const float* __restrict__ Wa3, const float* __restrict__ ba3,
    float* __restrict__ out)
{
  // per-wave: [0..511] double-buffered 4-record stage, [512..1375] G (col 35 = G0),
  //           [1376..1567] feat, [1568..1631] h
  __shared__ __align__(16) float sScr[2][1696];
  int tid = threadIdx.x;
  int lane = tid & 63, wv = tid >> 6;
  int a = blockIdx.x * 2 + wv;          // NATOMS = 5000*2 exact
  float* sStage = &sScr[wv][0];
  float* sG     = &sScr[wv][512];
  float* sFeat  = &sScr[wv][1376];
  float* sH     = &sScr[wv][1568];

  const int* offs = (const int*)(ws + WS_OFFS);
  const int* cnt  = (const int*)(ws + WS_CNT);
  const int* eidx = (const int*)(ws + WS_EIDX);
  int start = offs[a], len = cnt[a], end = start + len;

  const int c = lane;
  bool isc = (c < 35);
  int pa = 0, pb = 0, pcw = 0, lb = 0;
  if (isc) { pa = d_PWA[c]; pb = d_PWB[c]; pcw = d_PWC[c]; lb = d_LBLK[c]; }
  int rdir = lane - 35;
  bool isd = (rdir >= 0) && (rdir < 8);
  int rl = lane >> 4, fl = lane & 15;   // gather role: record rl, float4 fl
  // source array + offset: fl<6 -> SA[fl]; fl 6..12 -> SB[fl-6]; fl 13..15 -> dup SB[6]
  const float* gsrc = ws + (fl < 6 ? WS_SA : WS_SB);
  int foff = (fl < 6) ? fl : ((fl < 13) ? fl - 6 : 6);
  // LDS landing slot fl*4 reproduces the 52-float record layout (B maps to 24+(fl-6)*4)

  float gc[3][8];
  #pragma unroll
  for (int t2 = 0; t2 < 3; t2++)
    #pragma unroll
    for (int r = 0; r < 8; r++) gc[t2][r] = 0.0f;
  float g0[3] = {0.0f, 0.0f, 0.0f};

#define CORE(T)                                                               \
  if (isc) {                                                                  \
    float4 rt = *(const float4*)(rb + 48);                                    \
    float comp = psel(rt.x, pa) * psel(rt.y, pb) * psel(rt.z, pcw);           \
    float4 Ra = *(const float4*)(rb + 8 + 8 * lb);                            \
    float4 Rb = *(const float4*)(rb + 12 + 8 * lb);                           \
    gc[T][0] += comp * Ra.x; gc[T][1] += comp * Ra.y;                         \
    gc[T][2] += comp * Ra.z; gc[T][3] += comp * Ra.w;                         \
    gc[T][4] += comp * Rb.x; gc[T][5] += comp * Rb.y;                         \
    gc[T][6] += comp * Rb.z; gc[T][7] += comp * Rb.w;                         \
  } else if (isd) {                                                           \
    g0[T] += rb[rdir];                                                        \
  }

  for (int cb = start; cb < end; cb += 64) {
    int m = end - cb; if (m > 64) m = 64;
    int pp = cb + lane;
    int packed = eidx[pp < end ? pp : start];     // coalesced chunk of indices
    // prefetch round 0 (4 records, 16 lanes each)
    int sl = rl; if (sl >= m) sl = m - 1;
    int pk = __shfl(packed, sl, 64);
    float4 v = *(const float4*)(gsrc + (size_t)(pk & 0xFFFFF) * 32 + foff * 4);
    for (int g = 0; g < m; g += 4) {
      float* buf = sStage + (((g >> 2) & 1) << 8);
      *(float4*)(buf + rl * 64 + fl * 4) = v;     // ds_write staged round
      if (g + 4 < m) {                            // prefetch next round into regs
        int sl2 = g + 4 + rl; if (sl2 >= m) sl2 = m - 1;
        int pk2 = __shfl(packed, sl2, 64);
        v = *(const float4*)(gsrc + (size_t)(pk2 & 0xFFFFF) * 32 + foff * 4);
      }
      int gm = m - g; if (gm > 4) gm = 4;
      for (int j = 0; j < gm; j++) {
        int t = __shfl(packed, g + j, 64) >> 20;  // wave-uniform species
        const float* rb = buf + j * 64;
        if (t == 0)      { CORE(0) }
        else if (t == 1) { CORE(1) }
        else             { CORE(2) }
      }
    }
  }
#undef CORE

  // transpose G into LDS (same-wave, no barrier)
  if (isc) {
    #pragma unroll
    for (int t2 = 0; t2 < 3; t2++)
      #pragma unroll
      for (int r = 0; r < 8; r++) sG[(t2 * 8 + r) * 36 + c] = gc[t2][r];
  } else if (isd) {
    #pragma unroll
    for (int t2 = 0; t2 < 3; t2++) sG[(t2 * 8 + rdir) * 36 + 35] = g0[t2];
  }

  // contraction: lane owns feats {lane, lane+64, lane+128}; f=(blk*8+rr)*4+s
  int s = lane & 3;
  float se0 = ws[WS_SEMB + s], se1 = ws[WS_SEMB + 4 + s], se2 = ws[WS_SEMB + 8 + s];
  float fout[3];
  #pragma unroll
  for (int u = 0; u < 3; u++) {
    int f = lane + 64 * u;
    int blk = f >> 5, rr = (f >> 2) & 7;
    float acc;
    if (blk == 0) {
      acc = se0 * sG[(0 + rr) * 36 + 35] + se1 * sG[(8 + rr) * 36 + 35] + se2 * sG[(16 + rr) * 36 + 35];
    } else {
      int c0 = d_L6[blk - 1], c1 = d_L6[blk];
      acc = 0.0f;
      for (int cc = c0; cc < c1; cc++) {
        float A = se0 * sG[(0 + rr) * 36 + cc] + se1 * sG[(8 + rr) * 36 + cc] + se2 * sG[(16 + rr) * 36 + cc];
        acc += d_NM_OK[cc] * A * A;
      }
    }
    fout[u] = acc;
  }
  #pragma unroll
  for (int u = 0; u < 3; u++) sFeat[lane + 64 * u] = fout[u];

  // MLP layer 1: 192 -> 64
  {
    float a0 = 0.f, a1 = 0.f, a2 = 0.f, a3 = 0.f;
    for (int k4 = 0; k4 < 48; k4++) {
      float4 f4 = *(const float4*)(sFeat + k4 * 4);
      const float* w = Wa1 + (k4 * 4) * 64 + lane;
      a0 += f4.x * w[0];
      a1 += f4.y * w[64];
      a2 += f4.z * w[128];
      a3 += f4.w * w[192];
    }
    sH[lane] = siluf(a0 + a1 + a2 + a3 + ba1[lane]);
  }

  // MLP layer 2: 64 -> 64, layer 3 + wave reduction
  {
    float a0 = 0.f, a1 = 0.f, a2 = 0.f, a3 = 0.f;
    for (int k4 = 0; k4 < 16; k4++) {
      float4 h4 = *(const float4*)(sH + k4 * 4);
      const float* w = Wa2 + (k4 * 4) * 64 + lane;
      a0 += h4.x * w[0];
      a1 += h4.y * w[64];
      a2 += h4.z * w[128];
      a3 += h4.w * w[192];
    }
    float h2 = siluf(a0 + a1 + a2 + a3 + ba2[lane]);
    float pr = h2 * Wa3[lane];
    #pragma unroll
    for (int off = 32; off > 0; off >>= 1) pr += __shfl_down(pr, off, 64);
    if (lane == 0) out[a] = pr + ba3[0];
  }
}

extern "C" void kernel_launch(void* const* d_in, const int* in_sizes, int n_in,
                              void* d_out, int out_size, void* d_ws, size_t ws_size,
                              hipStream_t stream)
{
  const float* rij         = (const float*)d_in[0];
  const int*   species     = (const int*)  d_in[1];
  const int*   first_atom  = (const int*)  d_in[2];
  const int*   second_atom = (const int*)  d_in[3];
  const float* Wr1 = (const float*)d_in[4];
  const float* br1 = (const float*)d_in[5];
  const float* Wr2 = (const float*)d_in[6];
  const float* br2 = (const float*)d_in[7];
  const float* Ws1 = (const float*)d_in[8];
  const float* bs1 = (const float*)d_in[9];
  const float* Ws2 = (const float*)d_in[10];
  const float* bs2 = (const float*)d_in[11];
  const float* Wa1 = (const float*)d_in[12];
  const float* ba1 = (const float*)d_in[13];
  const float* Wa2 = (const float*)d_in[14];
  const float* ba2 = (const float*)d_in[15];
  const float* Wa3 = (const float*)d_in[16];
  const float* ba3 = (const float*)d_in[17];
  float* ws  = (float*)d_ws;
  float* out = (float*)d_out;

  k_init<<<40, 256, 0, stream>>>(Ws1, bs1, Ws2, bs2, ws);
  k_hist<<<(NEDGES + 255) / 256, 256, 0, stream>>>(first_atom, ws);
  k_alloc<<<40, 256, 0, stream>>>(ws);
  k_edge<<<NEDGES / 256, 256, 0, stream>>>(rij, species, first_atom, second_atom,
                                           Wr1, br1, Wr2, br2, ws);
  k_atom<<<NATOMS / 2, 128, 0, stream>>>(ws, Wa1, ba1, Wa2, ba2, Wa3, ba3, out);
}